// Round 11
// baseline (239.787 us; speedup 1.0000x reference)
//
#include <hip/hip_runtime.h>
#include <math.h>

namespace {

constexpr int C_ = 3, T_ = 3000, F_ = 103, NB_ = 6;
constexpr int TT = 20;                       // t-steps per tile
constexpr int NT = 3;                        // tiles per block; 3000/(20*3)=50 chunks
constexpr int BS[NB_]  = {1, 10, 20, 30, 40, 61};
constexpr int BNB[NB_] = {10, 11, 11, 11, 22, 16};
constexpr int WB[NB_]  = {0, 5, 11, 17, 23, 34};    // packed-word offsets (cum ceil(nb/2))
constexpr int WBC[NB_] = {5, 6, 6, 6, 11, 8};       // packed words per band; total 42
constexpr int WROW = 42;                     // packed words per p=(c,n)
constexpr int WTOTU = 18 * WROW;             // 756 packed u32 weights
constexpr int SPF = 81;                      // staged spec cols (bands span f=1..76)
constexpr int PLANE = T_ * F_;               // 309000
constexpr int SECP = 2064;                   // enh plane stride (2060 padded to x4)
constexpr int POOL2 = 6192;                  // max(4860, 3*2064)

__device__ __forceinline__ float softplus_(float x) {
  return fmaxf(x, 0.0f) + log1pf(expf(-fabsf(x)));
}
__device__ __forceinline__ float sigmoid_(float z) {
  return 1.0f / (1.0f + __expf(-z));
}
__device__ __forceinline__ float gelu_(float x) {
  return x * sigmoid_(1.595769122f * x * (1.0f + 0.044715f * x * x));
}
__device__ __forceinline__ unsigned bf16_rne_(float x) {
  unsigned b = __float_as_uint(x);
  b += 0x7FFFu + ((b >> 16) & 1u);
  return b >> 16;
}

// ---- pre-kernel: packed bf16 gaussian bank + folded proj/BN -> d_ws -----------
// u32 view: [0..755] packed weight pairs (lo=tap 2e, hi=tap 2e+1) at p*42+WB[i]+e
// f32 view: [756..764] projBN w, [765..767] projBN b
__global__ __launch_bounds__(128)
void prep_kernel(const float* __restrict__ centers,
                 const float* __restrict__ widths,
                 const float* __restrict__ gains,
                 const float* __restrict__ proj_w,
                 const float* __restrict__ proj_b,
                 const float* __restrict__ bn_gamma,
                 const float* __restrict__ bn_beta,
                 const float* __restrict__ bn_mean,
                 const float* __restrict__ bn_var,
                 float* __restrict__ ws)
{
  unsigned* wsU = (unsigned*)ws;
  const int q = threadIdx.x;
  if (q < 108) {
    int i = q / 18;
    int p = q - i * 18;                       // c*6+n
    int s = BS[i], nb = BNB[i];
    float mu = softplus_(centers[q]) + (float)s;
    mu = fminf(fmaxf(mu, (float)s), (float)(s + nb - 1));
    float sd = softplus_(widths[q]) + 0.001f;
    sd = fminf(fmaxf(sd, 0.5f), 2.0f * (float)nb / 6.0f);
    float sum = 0.0f;
    for (int f = 0; f < nb; ++f) {
      float d = ((float)f - mu) / sd;
      sum += __expf(-0.5f * d * d);
    }
    float sc = gains[q] / (sum + 1e-6f);
    float wtmp[22];
    for (int f = 0; f < nb; ++f) {
      float d = ((float)f - mu) / sd;
      wtmp[f] = sc * __expf(-0.5f * d * d);
    }
    const int wc = (nb + 1) / 2;
    for (int e = 0; e < wc; ++e) {
      unsigned lo = bf16_rne_(wtmp[2 * e]);
      unsigned hi = (2 * e + 1 < nb) ? bf16_rne_(wtmp[2 * e + 1]) : 0u;
      wsU[p * WROW + WB[i] + e] = lo | (hi << 16);
    }
  } else if (q < 117) {
    int k = q - 108, d = k / 3;
    float sc = bn_gamma[d] / sqrtf(bn_var[d] + 1e-5f);
    ws[WTOTU + k] = proj_w[k] * sc;
  } else if (q < 120) {
    int d = q - 117;
    float sc = bn_gamma[d] / sqrtf(bn_var[d] + 1e-5f);
    ws[WTOTU + 9 + d] = (proj_b[d] - bn_mean[d]) * sc + bn_beta[d];
  }
}

// ---- main kernel: R10 structure, packed-bf16-weight n-pair Phase A ------------
__global__ __launch_bounds__(256)
void sleepband_kernel(const float* __restrict__ spec,
                      const float* __restrict__ ws,
                      const float* __restrict__ align_w,
                      const float* __restrict__ align_b,
                      const float* __restrict__ fc1_w,
                      const float* __restrict__ fc1_b,
                      const float* __restrict__ fc2_w,
                      const float* __restrict__ fc2_b,
                      const float* __restrict__ band_gain,
                      const float* __restrict__ gate_w,
                      const float* __restrict__ gate_b,
                      float* __restrict__ out)
{
  // pool: [stage/A] spec[C][TT][81] (4860)  ||  [B2/final] enh[3][SECP] (6192)
  __shared__ __align__(16) float sPool[POOL2];
  __shared__ unsigned sWu[WTOTU];        // packed bf16 weight pairs, persistent
  __shared__ float sBand[TT][109];       // odd stride -> conflict-free
  __shared__ float sAw[54], sAb[18], sF1[108], sF1b[6], sF2[108], sF2b[18],
                   sBg[6], sGw[9], sGb[3], sPw[9], sPb[3];

  const int tid = threadIdx.x;
  const int b   = blockIdx.y;
  const float* specB = spec + (size_t)b * C_ * PLANE;
  float* outBase = out + (size_t)b * C_ * PLANE;
  const unsigned* wsU = (const unsigned*)ws;

  // ---- one-time prologue: params + packed gaussian weights from d_ws ----
  for (int k = tid; k < WTOTU; k += 256) sWu[k] = wsU[k];
  if (tid < 54)  sAw[tid]  = align_w[tid];
  if (tid < 18)  sAb[tid]  = align_b[tid];
  if (tid < 108) sF1[tid]  = fc1_w[tid];
  if (tid < 6)   sF1b[tid] = fc1_b[tid];
  if (tid < 108) sF2[tid]  = fc2_w[tid];
  if (tid < 18)  sF2b[tid] = fc2_b[tid];
  if (tid < 6)   sBg[tid]  = band_gain[tid];
  if (tid < 9)   sGw[tid]  = gate_w[tid];
  if (tid < 3)   sGb[tid]  = gate_b[tid];
  if (tid < 9)   sPw[tid]  = ws[WTOTU + tid];
  if (tid < 3)   sPb[tid]  = ws[WTOTU + 9 + tid];

  for (int tile = 0; tile < NT; ++tile) {
    const int t0 = (blockIdx.x * NT + tile) * TT;

    // ---- stage spec band region (coalesced) ----
    for (int li = tid; li < C_ * TT * SPF; li += 256) {
      int c   = li / (TT * SPF);
      int rem = li - c * (TT * SPF);
      int tt  = rem / SPF;
      int f   = rem - tt * SPF;
      sPool[li] = specB[(size_t)c * PLANE + (size_t)(t0 + tt) * F_ + f];
    }
    __syncthreads();

    // ---- Phase A: filt via packed-bf16 weights, n-pair tasks (180) ----
    // task = (c, np, tt): 2 n outputs share each spec read; 1 weight word = 2 taps.
    if (tid < 180) {
      const int g  = tid / TT;             // c*3 + np
      const int tt = tid - g * TT;
      const int c  = g / 3;
      const int np = g - c * 3;
      const int n0 = 2 * np;
      const float* srow = &sPool[(c * TT + tt) * SPF];
      const unsigned* w0 = &sWu[(c * 6 + n0) * WROW];
      const unsigned* w1 = w0 + WROW;
      #pragma unroll
      for (int i = 0; i < NB_; ++i) {
        const float* sr = srow + BS[i];
        float a0 = 0.0f, a1 = 0.0f;
        #pragma unroll
        for (int e = 0; e < WBC[i]; ++e) {
          // beyond-band s1 read (odd nb) lands in-row and multiplies a zero pad.
          float s0 = sr[2 * e], s1 = sr[2 * e + 1];
          unsigned u0 = w0[WB[i] + e], u1 = w1[WB[i] + e];
          a0 += s0 * __uint_as_float(u0 << 16);
          a0 += s1 * __uint_as_float(u0 & 0xffff0000u);
          a1 += s0 * __uint_as_float(u1 << 16);
          a1 += s1 * __uint_as_float(u1 & 0xffff0000u);
        }
        sBand[tt][(i * 3 + c) * 6 + n0]     = a0;
        sBand[tt][(i * 3 + c) * 6 + n0 + 1] = a1;
      }
    }
    __syncthreads();

    // ---- Phase B: align + MLP + softmax + scale (6*TT tasks) ----
    if (tid < 6 * TT) {
      int n  = tid / TT;
      int tt = tid - n * TT;
      float al[18];
      #pragma unroll
      for (int i = 0; i < 6; ++i) {
        float f0 = sBand[tt][(i * 3 + 0) * 6 + n];
        float f1 = sBand[tt][(i * 3 + 1) * 6 + n];
        float f2 = sBand[tt][(i * 3 + 2) * 6 + n];
        #pragma unroll
        for (int d = 0; d < 3; ++d)
          al[i * 3 + d] = sAw[i * 9 + d * 3 + 0] * f0 + sAw[i * 9 + d * 3 + 1] * f1 +
                          sAw[i * 9 + d * 3 + 2] * f2 + sAb[i * 3 + d];
      }
      float h[6];
      #pragma unroll
      for (int o = 0; o < 6; ++o) {
        float acc = sF1b[o];
        #pragma unroll
        for (int k = 0; k < 18; ++k) acc += sF1[o * 18 + k] * al[k];
        h[o] = gelu_(acc);
      }
      float at[18];
      #pragma unroll
      for (int k = 0; k < 18; ++k) {
        float acc = sF2b[k];
        #pragma unroll
        for (int o = 0; o < 6; ++o) acc += sF2[k * 6 + o] * h[o];
        at[k] = acc;
      }
      #pragma unroll
      for (int c = 0; c < 3; ++c) {
        float m = at[c];
        #pragma unroll
        for (int i = 1; i < 6; ++i) m = fmaxf(m, at[i * 3 + c]);
        float e[6], ssum = 0.0f;
        #pragma unroll
        for (int i = 0; i < 6; ++i) { e[i] = __expf(at[i * 3 + c] - m); ssum += e[i]; }
        float inv = 1.0f / ssum;
        #pragma unroll
        for (int i = 0; i < 6; ++i)
          sBand[tt][(i * 3 + c) * 6 + n] = al[i * 3 + c] * (e[i] * inv) * sBg[i];
      }
    }
    __syncthreads();

    // ---- Phase B2: compile-time-tap upsample into dense enh ----
    if (tid < C_ * TT) {
      const int c  = tid / TT;
      const int tt = tid - c * TT;
      float bnd[36];
      #pragma unroll
      for (int i = 0; i < 6; ++i)
        #pragma unroll
        for (int n = 0; n < 6; ++n)
          bnd[i * 6 + n] = sBand[tt][(i * 3 + c) * 6 + n];
      float* row = &sPool[c * SECP + tt * F_];
      row[0] = 0.0f;
      float carry = 0.0f;
      #pragma unroll
      for (int i = 0; i < NB_; ++i) {
        #pragma unroll
        for (int j = 0; j < BNB[i]; ++j) {
          float src = ((float)j + 0.5f) * 6.0f / (float)BNB[i] - 0.5f;
          src = src > 0.0f ? src : 0.0f;
          int   x0 = (int)src;
          int   x1 = (x0 < 5) ? x0 + 1 : 5;
          float wl = src - (float)x0;
          float v  = bnd[i * 6 + x0] * (1.0f - wl) + bnd[i * 6 + x1] * wl;
          if (j == 0) v += carry;
          if (i < NB_ - 1 && j == BNB[i] - 1) carry = v;
          else row[BS[i] + j] = v;
        }
      }
      #pragma unroll
      for (int f = 77; f < F_; ++f) row[f] = 0.0f;
    }
    __syncthreads();

    // ---- Final: flat float4 gate + folded proj + gelu ----
    float gw[9], pw[9], gb3[3], pb3[3];
    #pragma unroll
    for (int k = 0; k < 9; ++k) { gw[k] = sGw[k]; pw[k] = sPw[k]; }
    #pragma unroll
    for (int k = 0; k < 3; ++k) { gb3[k] = sGb[k]; pb3[k] = sPb[k]; }

    const float* sp0 = specB + (size_t)t0 * F_;
    float* outB = outBase + (size_t)t0 * F_;
    for (int e4 = tid; e4 < (TT * F_) / 4; e4 += 256) {
      const int e = e4 * 4;
      const float4 sA = *(const float4*)(sp0 + e);
      const float4 sB = *(const float4*)(sp0 + PLANE + e);
      const float4 sC = *(const float4*)(sp0 + 2 * PLANE + e);
      const float4 eA = *(const float4*)&sPool[0 * SECP + e];
      const float4 eB = *(const float4*)&sPool[1 * SECP + e];
      const float4 eC = *(const float4*)&sPool[2 * SECP + e];
      float4 oA, oB, oC;
      const float* sAp = (const float*)&sA; const float* sBp = (const float*)&sB;
      const float* sCp = (const float*)&sC;
      const float* eAp = (const float*)&eA; const float* eBp = (const float*)&eB;
      const float* eCp = (const float*)&eC;
      float* oAp = (float*)&oA; float* oBp = (float*)&oB; float* oCp = (float*)&oC;
      #pragma unroll
      for (int j = 0; j < 4; ++j) {
        float sv0 = sAp[j], sv1 = sBp[j], sv2 = sCp[j];
        float r0 = eAp[j] - sv0, r1 = eBp[j] - sv1, r2 = eCp[j] - sv2;
        float e20 = sv0 + sigmoid_(gw[0] * r0 + gw[1] * r1 + gw[2] * r2 + gb3[0]) * r0;
        float e21 = sv1 + sigmoid_(gw[3] * r0 + gw[4] * r1 + gw[5] * r2 + gb3[1]) * r1;
        float e22 = sv2 + sigmoid_(gw[6] * r0 + gw[7] * r1 + gw[8] * r2 + gb3[2]) * r2;
        float y0 = pw[0] * e20 + pw[1] * e21 + pw[2] * e22 + pb3[0];
        float y1 = pw[3] * e20 + pw[4] * e21 + pw[5] * e22 + pb3[1];
        float y2 = pw[6] * e20 + pw[7] * e21 + pw[8] * e22 + pb3[2];
        oAp[j] = gelu_(y0); oBp[j] = gelu_(y1); oCp[j] = gelu_(y2);
      }
      *(float4*)(outB + e) = oA;
      *(float4*)(outB + PLANE + e) = oB;
      *(float4*)(outB + 2 * PLANE + e) = oC;
    }
    __syncthreads();   // protect sPool (enh) before next tile's staging
  }
}

} // namespace

extern "C" void kernel_launch(void* const* d_in, const int* in_sizes, int n_in,
                              void* d_out, int out_size, void* d_ws, size_t ws_size,
                              hipStream_t stream) {
  (void)n_in; (void)out_size; (void)ws_size;
  const int B = in_sizes[0] / (C_ * T_ * F_);   // 64
  float* ws = (float*)d_ws;                     // 756 u32 + 12 f32
  prep_kernel<<<1, 128, 0, stream>>>(
      (const float*)d_in[1],  (const float*)d_in[2],  (const float*)d_in[3],
      (const float*)d_in[13], (const float*)d_in[14], (const float*)d_in[15],
      (const float*)d_in[16], (const float*)d_in[17], (const float*)d_in[18], ws);
  dim3 grid(T_ / (TT * NT), B);                 // (50, 64)
  sleepband_kernel<<<grid, 256, 0, stream>>>(
      (const float*)d_in[0],  ws,
      (const float*)d_in[4],  (const float*)d_in[5],
      (const float*)d_in[6],  (const float*)d_in[7],  (const float*)d_in[8],
      (const float*)d_in[9],  (const float*)d_in[10], (const float*)d_in[11],
      (const float*)d_in[12], (float*)d_out);
}